// Round 5
// baseline (239.866 us; speedup 1.0000x reference)
//
#include <hip/hip_runtime.h>
#include <hip/hip_bf16.h>

// LSTM cell, B=4096, IN=1024, H=1024, K = IN+H = 2048. All I/O float32.
// Pass 1 convert_pack: X=concat(input,hx) -> bf16 Xb; W -> bf16 Wp (rows
//   permuted to (gate,hn)-interleaved tile order).
// Pass 2 lstm_gemm: 128x128 MFMA GEMM, global_load_lds staging,
//   XOR-swizzled LDS slots (conflict-free ds_read_b128), DOUBLE-BUFFERED
//   single-barrier K-loop (DMA for tile t+1 in flight during compute of
//   tile t), fused LSTM gating epilogue. fp32 accumulate/output.

typedef __attribute__((ext_vector_type(8))) __bf16 bf16x8;
typedef __attribute__((ext_vector_type(4))) float f32x4;

__device__ __forceinline__ unsigned short f2bf(float f) {
  union { float f; unsigned int u; } v; v.f = f;
  unsigned int u = v.u + 0x7FFF + ((v.u >> 16) & 1);  // round-to-nearest-even
  return (unsigned short)(u >> 16);
}
__device__ __forceinline__ unsigned int pack2(float a, float b) {
  return (unsigned int)f2bf(a) | ((unsigned int)f2bf(b) << 16);
}

__device__ __forceinline__ void gld_lds16(const void* g, void* l) {
  __builtin_amdgcn_global_load_lds(
      (const __attribute__((address_space(1))) unsigned int*)g,
      (__attribute__((address_space(3))) unsigned int*)l, 16, 0, 0);
}

__device__ __forceinline__ float sigmoidf_fast(float x) {
  return 1.0f / (1.0f + __expf(-x));
}
__device__ __forceinline__ float tanhf_fast(float x) {
  return 1.0f - 2.0f / (__expf(2.0f * x) + 1.0f);
}

// ---------------- Pass 1: fp32 -> bf16 conversion + W permutation ----------
__global__ __launch_bounds__(256) void convert_pack(
    const float* __restrict__ xin, const float* __restrict__ hx,
    const float* __restrict__ Wi, const float* __restrict__ Wf,
    const float* __restrict__ Wg, const float* __restrict__ Wo,
    unsigned short* __restrict__ Xb, unsigned short* __restrict__ Wp) {
  const int t = blockIdx.x * 256 + threadIdx.x;
  const float* src;
  unsigned short* dst;
  if (t < (1 << 20)) {
    const int e = t * 8;
    const int row = e >> 11, k = e & 2047;
    src = (k < 1024) ? (xin + (size_t)row * 1024 + k)
                     : (hx + (size_t)row * 1024 + (k - 1024));
    dst = Xb + e;
  } else {
    const int e = (t - (1 << 20)) * 8;
    const int g_rb = e >> 11, k = e & 2047;
    const int nb = g_rb >> 7, rb = g_rb & 127;
    const int gate = (rb >> 4) & 3;
    const int hn = (rb >> 6) * 16 + (rb & 15);
    const float* W = gate == 0 ? Wi : (gate == 1 ? Wf : (gate == 2 ? Wg : Wo));
    src = W + (size_t)(nb * 32 + hn) * 2048 + k;
    dst = Wp + e;
  }
  const float4 lo = *(const float4*)src;
  const float4 hi = *(const float4*)(src + 4);
  uint4 p;
  p.x = pack2(lo.x, lo.y);
  p.y = pack2(lo.z, lo.w);
  p.z = pack2(hi.x, hi.y);
  p.w = pack2(hi.z, hi.w);
  *(uint4*)dst = p;
}

// ---------------- Pass 2: MFMA GEMM + fused LSTM gating --------------------
__global__ __launch_bounds__(256) void lstm_gemm(
    const unsigned short* __restrict__ Xb, const unsigned short* __restrict__ Wp,
    const float* __restrict__ cx,
    const float* __restrict__ bi, const float* __restrict__ bfv,
    const float* __restrict__ bg, const float* __restrict__ bo,
    float* __restrict__ out) {
  __shared__ unsigned short As[2][128 * 32];  // X tiles, XOR-swizzled slots
  __shared__ unsigned short Bs[2][128 * 32];  // W tiles, XOR-swizzled slots

  const int tid = threadIdx.x;
  const int lane = tid & 63;
  const int wid = tid >> 6;
  const int wr = wid >> 1, wc = wid & 1;
  const int lane15 = lane & 15, quad = lane >> 4;
  const int qsw = quad ^ ((lane15 >> 1) & 3);  // swizzled quad for frag reads

  const int mbase = blockIdx.x * 128;  // batch tile
  const int nb = blockIdx.y;           // hidden-col tile (32 cols)
  const int nbase = nb * 32;

  // staging: thread owns LDS slots s0=tid, s1=tid+256 (within each buffer).
  // slot s holds global chunk (row = s>>2, j = (s&3)^((s>>3)&3)).
  const int s0 = tid, s1 = tid + 256;
  const int r0 = s0 >> 2, j0 = (s0 & 3) ^ ((s0 >> 3) & 3);
  const int r1 = s1 >> 2, j1 = (s1 & 3) ^ ((s1 >> 3) & 3);
  const unsigned short* asrc0 = Xb + (size_t)(mbase + r0) * 2048 + j0 * 8;
  const unsigned short* asrc1 = Xb + (size_t)(mbase + r1) * 2048 + j1 * 8;
  const unsigned short* bsrc0 = Wp + (size_t)(nb * 128 + r0) * 2048 + j0 * 8;
  const unsigned short* bsrc1 = Wp + (size_t)(nb * 128 + r1) * 2048 + j1 * 8;

  f32x4 acc[4][4] = {};

  // stage tile 0 into buffer 0
  gld_lds16(asrc0, As[0] + s0 * 8);
  gld_lds16(asrc1, As[0] + s1 * 8);
  gld_lds16(bsrc0, Bs[0] + s0 * 8);
  gld_lds16(bsrc1, Bs[0] + s1 * 8);

  const int aro = (wr * 64 + lane15) * 32 + qsw * 8;  // A frag base (row i=0)
  const int bro = (wc * 64 + lane15) * 32 + qsw * 8;  // B frag base (col j=0)

#define COMPUTE(BUF)                                                           \
  {                                                                            \
    bf16x8 a[4], b[4];                                                         \
    _Pragma("unroll") for (int i = 0; i < 4; ++i) a[i] =                       \
        *reinterpret_cast<const bf16x8*>(&As[BUF][aro + i * 16 * 32]);         \
    _Pragma("unroll") for (int j = 0; j < 4; ++j) b[j] =                       \
        *reinterpret_cast<const bf16x8*>(&Bs[BUF][bro + j * 16 * 32]);         \
    _Pragma("unroll") for (int i = 0; i < 4; ++i)                              \
        _Pragma("unroll") for (int j = 0; j < 4; ++j) acc[i][j] =              \
            __builtin_amdgcn_mfma_f32_16x16x32_bf16(a[i], b[j], acc[i][j],     \
                                                    0, 0, 0);                  \
  }

  for (int kt = 0; kt < 64; kt += 2) {
    // ---- even iter: compute buf0, prefetch tile kt+1 -> buf1
    __syncthreads();  // drains buf0 DMA (issued prev iter) + buf1 reads done
    {
      const int kc = (kt + 1) * 32;  // kt+1 <= 63 always
      gld_lds16(asrc0 + kc, As[1] + s0 * 8);
      gld_lds16(asrc1 + kc, As[1] + s1 * 8);
      gld_lds16(bsrc0 + kc, Bs[1] + s0 * 8);
      gld_lds16(bsrc1 + kc, Bs[1] + s1 * 8);
    }
    COMPUTE(0)

    // ---- odd iter: compute buf1, prefetch tile kt+2 -> buf0
    __syncthreads();  // drains buf1 DMA + buf0 reads done
    if (kt + 2 < 64) {
      const int kc = (kt + 2) * 32;
      gld_lds16(asrc0 + kc, As[0] + s0 * 8);
      gld_lds16(asrc1 + kc, As[0] + s1 * 8);
      gld_lds16(bsrc0 + kc, Bs[0] + s0 * 8);
      gld_lds16(bsrc1 + kc, Bs[0] + s1 * 8);
    }
    COMPUTE(1)
  }
#undef COMPUTE

  // fused LSTM epilogue: acc[i][j], j = gate (0:i 1:f 2:g 3:o);
  // C layout: col=lane&15, row=quad*4+reg
  const int n = nbase + wc * 16 + lane15;
  const float bias_i = bi[n];
  const float bias_f = bfv[n];
  const float bias_g = bg[n];
  const float bias_o = bo[n];

  float* outh = out;
  float* outc = out + (size_t)4096 * 1024;

#pragma unroll
  for (int i = 0; i < 4; ++i) {
#pragma unroll
    for (int r = 0; r < 4; ++r) {
      const int mb = mbase + wr * 64 + i * 16 + quad * 4 + r;
      const size_t idx = (size_t)mb * 1024 + n;
      const float it = sigmoidf_fast(acc[i][0][r] + bias_i);
      const float ft = sigmoidf_fast(acc[i][1][r] + bias_f);
      const float gt = tanhf_fast(acc[i][2][r] + bias_g);
      const float ot = sigmoidf_fast(acc[i][3][r] + bias_o);
      const float cv = ft * cx[idx] + it * gt;
      const float hv = ot * tanhf_fast(cv);
      outh[idx] = hv;
      outc[idx] = cv;
    }
  }
}

// ---------------- Fallback (R2): single fused kernel, no workspace ----------
__global__ __launch_bounds__(256) void lstm_fused_fb(
    const float* __restrict__ xin, const float* __restrict__ hx,
    const float* __restrict__ cx,
    const float* __restrict__ Wi, const float* __restrict__ bi,
    const float* __restrict__ Wf, const float* __restrict__ bfv,
    const float* __restrict__ Wg, const float* __restrict__ bg,
    const float* __restrict__ Wo, const float* __restrict__ bo,
    float* __restrict__ out) {
  __shared__ unsigned short As[128 * 32];
  __shared__ unsigned short Bs[128 * 32];

  const int tid = threadIdx.x;
  const int lane = tid & 63;
  const int wid = tid >> 6;
  const int wr = wid >> 1, wc = wid & 1;
  const int lane15 = lane & 15, quad = lane >> 4;
  const int mbase = blockIdx.x * 128;
  const int nbase = blockIdx.y * 32;

  const int kofs = (tid & 3) * 8;
  const size_t a_off0 = (size_t)(mbase + (tid >> 2)) * 1024 + kofs;
  const size_t a_off1 = a_off0 + (size_t)64 * 1024;

  auto wsel = [&](int g) { return g == 0 ? Wi : (g == 1 ? Wf : (g == 2 ? Wg : Wo)); };
  const int rb0 = tid >> 2;
  const int rb1 = rb0 + 64;
  const float* bsrc0 =
      wsel((rb0 >> 4) & 3) + (size_t)(nbase + (rb0 >> 6) * 16 + (rb0 & 15)) * 2048 + kofs;
  const float* bsrc1 =
      wsel((rb1 >> 4) & 3) + (size_t)(nbase + (rb1 >> 6) * 16 + (rb1 & 15)) * 2048 + kofs;

  uint4* lA0 = (uint4*)(As + (size_t)tid * 8);
  uint4* lA1 = (uint4*)(As + (size_t)(tid + 256) * 8);
  uint4* lB0 = (uint4*)(Bs + (size_t)tid * 8);
  uint4* lB1 = (uint4*)(Bs + (size_t)(tid + 256) * 8);

  f32x4 acc[4][4] = {};

  for (int kt = 0; kt < 64; ++kt) {
    const int kc = kt * 32;
    const float* abase = (kc < 1024 ? xin : hx) + (kc & 1023);
    const float4 a0lo = *(const float4*)(abase + a_off0);
    const float4 a0hi = *(const float4*)(abase + a_off0 + 4);
    const float4 a1lo = *(const float4*)(abase + a_off1);
    const float4 a1hi = *(const float4*)(abase + a_off1 + 4);
    const float4 b0lo = *(const float4*)(bsrc0 + kc);
    const float4 b0hi = *(const float4*)(bsrc0 + kc + 4);
    const float4 b1lo = *(const float4*)(bsrc1 + kc);
    const float4 b1hi = *(const float4*)(bsrc1 + kc + 4);

    uint4 pa0, pa1, pb0, pb1;
    pa0.x = pack2(a0lo.x, a0lo.y); pa0.y = pack2(a0lo.z, a0lo.w);
    pa0.z = pack2(a0hi.x, a0hi.y); pa0.w = pack2(a0hi.z, a0hi.w);
    pa1.x = pack2(a1lo.x, a1lo.y); pa1.y = pack2(a1lo.z, a1lo.w);
    pa1.z = pack2(a1hi.x, a1hi.y); pa1.w = pack2(a1hi.z, a1hi.w);
    pb0.x = pack2(b0lo.x, b0lo.y); pb0.y = pack2(b0lo.z, b0lo.w);
    pb0.z = pack2(b0hi.x, b0hi.y); pb0.w = pack2(b0hi.z, b0hi.w);
    pb1.x = pack2(b1lo.x, b1lo.y); pb1.y = pack2(b1lo.z, b1lo.w);
    pb1.z = pack2(b1hi.x, b1hi.y); pb1.w = pack2(b1hi.z, b1hi.w);

    __syncthreads();
    *lA0 = pa0; *lA1 = pa1; *lB0 = pb0; *lB1 = pb1;
    __syncthreads();

    bf16x8 a[4], b[4];
#pragma unroll
    for (int i = 0; i < 4; ++i)
      a[i] = *reinterpret_cast<const bf16x8*>(&As[(wr * 64 + i * 16 + lane15) * 32 + quad * 8]);
#pragma unroll
    for (int j = 0; j < 4; ++j)
      b[j] = *reinterpret_cast<const bf16x8*>(&Bs[(wc * 64 + j * 16 + lane15) * 32 + quad * 8]);
#pragma unroll
    for (int i = 0; i < 4; ++i)
#pragma unroll
      for (int j = 0; j < 4; ++j)
        acc[i][j] = __builtin_amdgcn_mfma_f32_16x16x32_bf16(a[i], b[j], acc[i][j], 0, 0, 0);
  }

  const int n = nbase + wc * 16 + lane15;
  const float bias_i = bi[n];
  const float bias_f = bfv[n];
  const float bias_g = bg[n];
  const float bias_o = bo[n];
  float* outh = out;
  float* outc = out + (size_t)4096 * 1024;

#pragma unroll
  for (int i = 0; i < 4; ++i) {
#pragma unroll
    for (int r = 0; r < 4; ++r) {
      const int mb = mbase + wr * 64 + i * 16 + quad * 4 + r;
      const size_t idx = (size_t)mb * 1024 + n;
      const float it = sigmoidf_fast(acc[i][0][r] + bias_i);
      const float ft = sigmoidf_fast(acc[i][1][r] + bias_f);
      const float gt = tanhf_fast(acc[i][2][r] + bias_g);
      const float ot = sigmoidf_fast(acc[i][3][r] + bias_o);
      const float cv = ft * cx[idx] + it * gt;
      const float hv = ot * tanhf_fast(cv);
      outh[idx] = hv;
      outc[idx] = cv;
    }
  }
}

extern "C" void kernel_launch(void* const* d_in, const int* in_sizes, int n_in,
                              void* d_out, int out_size, void* d_ws, size_t ws_size,
                              hipStream_t stream) {
  const float* xin = (const float*)d_in[0];
  const float* hx  = (const float*)d_in[1];
  const float* cx  = (const float*)d_in[2];
  const float* Wi  = (const float*)d_in[3];
  const float* bi  = (const float*)d_in[4];
  const float* Wf  = (const float*)d_in[5];
  const float* bf  = (const float*)d_in[6];
  const float* Wg  = (const float*)d_in[7];
  const float* bg  = (const float*)d_in[8];
  const float* Wo  = (const float*)d_in[9];
  const float* bo  = (const float*)d_in[10];
  float* out = (float*)d_out;

  const size_t need = (size_t)2 * 4096 * 2048 * sizeof(unsigned short);  // 32 MB
  if (ws_size >= need) {
    unsigned short* Xb = (unsigned short*)d_ws;
    unsigned short* Wp = Xb + (size_t)4096 * 2048;
    convert_pack<<<8192, 256, 0, stream>>>(xin, hx, Wi, Wf, Wg, Wo, Xb, Wp);
    dim3 grid(4096 / 128, 1024 / 32);
    lstm_gemm<<<grid, 256, 0, stream>>>(Xb, Wp, cx, bi, bf, bg, bo, out);
  } else {
    dim3 grid(4096 / 128, 1024 / 32);
    lstm_fused_fb<<<grid, 256, 0, stream>>>(xin, hx, cx, Wi, bi, Wf, bf, Wg, bg, Wo, bo, out);
  }
}

// Round 6
// 220.420 us; speedup vs baseline: 1.0882x; 1.0882x over previous
//
#include <hip/hip_runtime.h>
#include <hip/hip_bf16.h>

// LSTM cell, B=4096, IN=1024, H=1024, K = IN+H = 2048. All I/O float32.
// Pass 1 convert_pack: X=concat(input,hx) -> bf16 Xb; W -> bf16 Wp (rows
//   permuted to (gate,hn)-interleaved tile order).
// Pass 2 lstm_gemm: 128x128 MFMA GEMM, BK=64, single-buffer 2-barrier K-loop
//   (R4 structure; dbuf regressed in R5), global_load_lds staging with 8-slot
//   XOR swizzle (conflict-free ds_read_b128), fused LSTM gating epilogue.
//   fp32 accumulate/output.
//
// Swizzle (BK=64): row has 8 16B-chunks; LDS slot s holds chunk
// j = (s&7) ^ ((s>>3)&7) of row s>>3. Fragment (row, k2, quad) reads chunk
// c = k2*4+quad at slot row*8 + (c ^ (row&7)); row&7 == lane15&7 within a
// 16-row MFMA tile, so the 8-lane LDS groups hit all 8 bank-quads.

typedef __attribute__((ext_vector_type(8))) __bf16 bf16x8;
typedef __attribute__((ext_vector_type(4))) float f32x4;

__device__ __forceinline__ unsigned short f2bf(float f) {
  union { float f; unsigned int u; } v; v.f = f;
  unsigned int u = v.u + 0x7FFF + ((v.u >> 16) & 1);  // round-to-nearest-even
  return (unsigned short)(u >> 16);
}
__device__ __forceinline__ unsigned int pack2(float a, float b) {
  return (unsigned int)f2bf(a) | ((unsigned int)f2bf(b) << 16);
}

__device__ __forceinline__ void gld_lds16(const void* g, void* l) {
  __builtin_amdgcn_global_load_lds(
      (const __attribute__((address_space(1))) unsigned int*)g,
      (__attribute__((address_space(3))) unsigned int*)l, 16, 0, 0);
}

__device__ __forceinline__ float sigmoidf_fast(float x) {
  return 1.0f / (1.0f + __expf(-x));
}
__device__ __forceinline__ float tanhf_fast(float x) {
  return 1.0f - 2.0f / (__expf(2.0f * x) + 1.0f);
}

// ---------------- Pass 1: fp32 -> bf16 conversion + W permutation ----------
__global__ __launch_bounds__(256) void convert_pack(
    const float* __restrict__ xin, const float* __restrict__ hx,
    const float* __restrict__ Wi, const float* __restrict__ Wf,
    const float* __restrict__ Wg, const float* __restrict__ Wo,
    unsigned short* __restrict__ Xb, unsigned short* __restrict__ Wp) {
  const int t = blockIdx.x * 256 + threadIdx.x;
  const float* src;
  unsigned short* dst;
  if (t < (1 << 20)) {
    const int e = t * 8;
    const int row = e >> 11, k = e & 2047;
    src = (k < 1024) ? (xin + (size_t)row * 1024 + k)
                     : (hx + (size_t)row * 1024 + (k - 1024));
    dst = Xb + e;
  } else {
    const int e = (t - (1 << 20)) * 8;
    const int g_rb = e >> 11, k = e & 2047;
    const int nb = g_rb >> 7, rb = g_rb & 127;
    const int gate = (rb >> 4) & 3;
    const int hn = (rb >> 6) * 16 + (rb & 15);
    const float* W = gate == 0 ? Wi : (gate == 1 ? Wf : (gate == 2 ? Wg : Wo));
    src = W + (size_t)(nb * 32 + hn) * 2048 + k;
    dst = Wp + e;
  }
  const float4 lo = *(const float4*)src;
  const float4 hi = *(const float4*)(src + 4);
  uint4 p;
  p.x = pack2(lo.x, lo.y);
  p.y = pack2(lo.z, lo.w);
  p.z = pack2(hi.x, hi.y);
  p.w = pack2(hi.z, hi.w);
  *(uint4*)dst = p;
}

// ---------------- Pass 2: MFMA GEMM + fused LSTM gating --------------------
__global__ __launch_bounds__(256) void lstm_gemm(
    const unsigned short* __restrict__ Xb, const unsigned short* __restrict__ Wp,
    const float* __restrict__ cx,
    const float* __restrict__ bi, const float* __restrict__ bfv,
    const float* __restrict__ bg, const float* __restrict__ bo,
    float* __restrict__ out) {
  __shared__ unsigned short As[128 * 64];  // X tile (BK=64), swizzled slots
  __shared__ unsigned short Bs[128 * 64];  // W tile (BK=64), swizzled slots

  const int tid = threadIdx.x;
  const int lane = tid & 63;
  const int wid = tid >> 6;
  const int wr = wid >> 1, wc = wid & 1;
  const int lane15 = lane & 15, quad = lane >> 4;
  const int l7 = lane15 & 7;
  const int cs0 = quad ^ l7;  // swizzled chunk for k2=0; k2=1 is cs0^4

  const int mbase = blockIdx.x * 128;  // batch tile
  const int nb = blockIdx.y;           // hidden-col tile (32 cols)
  const int nbase = nb * 32;

  // staging: thread owns slots s = tid + 256*d, d=0..3, per operand.
  // slot s: row = s>>3, stored chunk j = (s&7) ^ (row&7).
  // For s = tid + 256d: row = (tid>>3) + 32d, j = (tid&7)^((tid>>3)&7)
  // (constant in d) -> sources are affine: base + d*32*2048 elements.
  const int r_base = tid >> 3;
  const int j_sw = (tid & 7) ^ (r_base & 7);
  const unsigned short* asrc = Xb + (size_t)(mbase + r_base) * 2048 + j_sw * 8;
  const unsigned short* bsrc = Wp + (size_t)(nb * 128 + r_base) * 2048 + j_sw * 8;
  unsigned short* lA = As + tid * 8;
  unsigned short* lB = Bs + tid * 8;

  f32x4 acc[4][4] = {};

  const int aro = (wr * 64 + lane15) * 64;  // A frag row base (shorts)
  const int bro = (wc * 64 + lane15) * 64;  // B frag row base

  for (int kt = 0; kt < 32; ++kt) {
    const int kc = kt * 64;
#pragma unroll
    for (int d = 0; d < 4; ++d) {
      gld_lds16(asrc + (size_t)d * (32 * 2048) + kc, lA + d * 2048);
      gld_lds16(bsrc + (size_t)d * (32 * 2048) + kc, lB + d * 2048);
    }
    __syncthreads();  // DMA landed + all waves staged

#pragma unroll
    for (int k2 = 0; k2 < 2; ++k2) {
      const int cs = (cs0 ^ (k2 * 4)) * 8;
      bf16x8 a[4], b[4];
#pragma unroll
      for (int i = 0; i < 4; ++i)
        a[i] = *reinterpret_cast<const bf16x8*>(&As[aro + i * 16 * 64 + cs]);
#pragma unroll
      for (int j = 0; j < 4; ++j)
        b[j] = *reinterpret_cast<const bf16x8*>(&Bs[bro + j * 16 * 64 + cs]);
#pragma unroll
      for (int i = 0; i < 4; ++i)
#pragma unroll
        for (int j = 0; j < 4; ++j)
          acc[i][j] = __builtin_amdgcn_mfma_f32_16x16x32_bf16(a[i], b[j],
                                                              acc[i][j], 0, 0, 0);
    }
    __syncthreads();  // reads done before next iter's DMA overwrites
  }

  // fused LSTM epilogue: acc[i][j], j = gate (0:i 1:f 2:g 3:o);
  // C layout: col=lane&15, row=quad*4+reg
  const int n = nbase + wc * 16 + lane15;
  const float bias_i = bi[n];
  const float bias_f = bfv[n];
  const float bias_g = bg[n];
  const float bias_o = bo[n];

  float* outh = out;
  float* outc = out + (size_t)4096 * 1024;

#pragma unroll
  for (int i = 0; i < 4; ++i) {
#pragma unroll
    for (int r = 0; r < 4; ++r) {
      const int mb = mbase + wr * 64 + i * 16 + quad * 4 + r;
      const size_t idx = (size_t)mb * 1024 + n;
      const float it = sigmoidf_fast(acc[i][0][r] + bias_i);
      const float ft = sigmoidf_fast(acc[i][1][r] + bias_f);
      const float gt = tanhf_fast(acc[i][2][r] + bias_g);
      const float ot = sigmoidf_fast(acc[i][3][r] + bias_o);
      const float cv = ft * cx[idx] + it * gt;
      const float hv = ot * tanhf_fast(cv);
      outh[idx] = hv;
      outc[idx] = cv;
    }
  }
}

// ---------------- Fallback (R2): single fused kernel, no workspace ----------
__global__ __launch_bounds__(256) void lstm_fused_fb(
    const float* __restrict__ xin, const float* __restrict__ hx,
    const float* __restrict__ cx,
    const float* __restrict__ Wi, const float* __restrict__ bi,
    const float* __restrict__ Wf, const float* __restrict__ bfv,
    const float* __restrict__ Wg, const float* __restrict__ bg,
    const float* __restrict__ Wo, const float* __restrict__ bo,
    float* __restrict__ out) {
  __shared__ unsigned short As[128 * 32];
  __shared__ unsigned short Bs[128 * 32];

  const int tid = threadIdx.x;
  const int lane = tid & 63;
  const int wid = tid >> 6;
  const int wr = wid >> 1, wc = wid & 1;
  const int lane15 = lane & 15, quad = lane >> 4;
  const int mbase = blockIdx.x * 128;
  const int nbase = blockIdx.y * 32;

  const int kofs = (tid & 3) * 8;
  const size_t a_off0 = (size_t)(mbase + (tid >> 2)) * 1024 + kofs;
  const size_t a_off1 = a_off0 + (size_t)64 * 1024;

  auto wsel = [&](int g) { return g == 0 ? Wi : (g == 1 ? Wf : (g == 2 ? Wg : Wo)); };
  const int rb0 = tid >> 2;
  const int rb1 = rb0 + 64;
  const float* bsrc0 =
      wsel((rb0 >> 4) & 3) + (size_t)(nbase + (rb0 >> 6) * 16 + (rb0 & 15)) * 2048 + kofs;
  const float* bsrc1 =
      wsel((rb1 >> 4) & 3) + (size_t)(nbase + (rb1 >> 6) * 16 + (rb1 & 15)) * 2048 + kofs;

  uint4* lA0 = (uint4*)(As + (size_t)tid * 8);
  uint4* lA1 = (uint4*)(As + (size_t)(tid + 256) * 8);
  uint4* lB0 = (uint4*)(Bs + (size_t)tid * 8);
  uint4* lB1 = (uint4*)(Bs + (size_t)(tid + 256) * 8);

  f32x4 acc[4][4] = {};

  for (int kt = 0; kt < 64; ++kt) {
    const int kc = kt * 32;
    const float* abase = (kc < 1024 ? xin : hx) + (kc & 1023);
    const float4 a0lo = *(const float4*)(abase + a_off0);
    const float4 a0hi = *(const float4*)(abase + a_off0 + 4);
    const float4 a1lo = *(const float4*)(abase + a_off1);
    const float4 a1hi = *(const float4*)(abase + a_off1 + 4);
    const float4 b0lo = *(const float4*)(bsrc0 + kc);
    const float4 b0hi = *(const float4*)(bsrc0 + kc + 4);
    const float4 b1lo = *(const float4*)(bsrc1 + kc);
    const float4 b1hi = *(const float4*)(bsrc1 + kc + 4);

    uint4 pa0, pa1, pb0, pb1;
    pa0.x = pack2(a0lo.x, a0lo.y); pa0.y = pack2(a0lo.z, a0lo.w);
    pa0.z = pack2(a0hi.x, a0hi.y); pa0.w = pack2(a0hi.z, a0hi.w);
    pa1.x = pack2(a1lo.x, a1lo.y); pa1.y = pack2(a1lo.z, a1lo.w);
    pa1.z = pack2(a1hi.x, a1hi.y); pa1.w = pack2(a1hi.z, a1hi.w);
    pb0.x = pack2(b0lo.x, b0lo.y); pb0.y = pack2(b0lo.z, b0lo.w);
    pb0.z = pack2(b0hi.x, b0hi.y); pb0.w = pack2(b0hi.z, b0hi.w);
    pb1.x = pack2(b1lo.x, b1lo.y); pb1.y = pack2(b1lo.z, b1lo.w);
    pb1.z = pack2(b1hi.x, b1hi.y); pb1.w = pack2(b1hi.z, b1hi.w);

    __syncthreads();
    *lA0 = pa0; *lA1 = pa1; *lB0 = pb0; *lB1 = pb1;
    __syncthreads();

    bf16x8 a[4], b[4];
#pragma unroll
    for (int i = 0; i < 4; ++i)
      a[i] = *reinterpret_cast<const bf16x8*>(&As[(wr * 64 + i * 16 + lane15) * 32 + quad * 8]);
#pragma unroll
    for (int j = 0; j < 4; ++j)
      b[j] = *reinterpret_cast<const bf16x8*>(&Bs[(wc * 64 + j * 16 + lane15) * 32 + quad * 8]);
#pragma unroll
    for (int i = 0; i < 4; ++i)
#pragma unroll
      for (int j = 0; j < 4; ++j)
        acc[i][j] = __builtin_amdgcn_mfma_f32_16x16x32_bf16(a[i], b[j], acc[i][j], 0, 0, 0);
  }

  const int n = nbase + wc * 16 + lane15;
  const float bias_i = bi[n];
  const float bias_f = bfv[n];
  const float bias_g = bg[n];
  const float bias_o = bo[n];
  float* outh = out;
  float* outc = out + (size_t)4096 * 1024;

#pragma unroll
  for (int i = 0; i < 4; ++i) {
#pragma unroll
    for (int r = 0; r < 4; ++r) {
      const int mb = mbase + wr * 64 + i * 16 + quad * 4 + r;
      const size_t idx = (size_t)mb * 1024 + n;
      const float it = sigmoidf_fast(acc[i][0][r] + bias_i);
      const float ft = sigmoidf_fast(acc[i][1][r] + bias_f);
      const float gt = tanhf_fast(acc[i][2][r] + bias_g);
      const float ot = sigmoidf_fast(acc[i][3][r] + bias_o);
      const float cv = ft * cx[idx] + it * gt;
      const float hv = ot * tanhf_fast(cv);
      outh[idx] = hv;
      outc[idx] = cv;
    }
  }
}

extern "C" void kernel_launch(void* const* d_in, const int* in_sizes, int n_in,
                              void* d_out, int out_size, void* d_ws, size_t ws_size,
                              hipStream_t stream) {
  const float* xin = (const float*)d_in[0];
  const float* hx  = (const float*)d_in[1];
  const float* cx  = (const float*)d_in[2];
  const float* Wi  = (const float*)d_in[3];
  const float* bi  = (const float*)d_in[4];
  const float* Wf  = (const float*)d_in[5];
  const float* bf  = (const float*)d_in[6];
  const float* Wg  = (const float*)d_in[7];
  const float* bg  = (const float*)d_in[8];
  const float* Wo  = (const float*)d_in[9];
  const float* bo  = (const float*)d_in[10];
  float* out = (float*)d_out;

  const size_t need = (size_t)2 * 4096 * 2048 * sizeof(unsigned short);  // 32 MB
  if (ws_size >= need) {
    unsigned short* Xb = (unsigned short*)d_ws;
    unsigned short* Wp = Xb + (size_t)4096 * 2048;
    convert_pack<<<8192, 256, 0, stream>>>(xin, hx, Wi, Wf, Wg, Wo, Xb, Wp);
    dim3 grid(4096 / 128, 1024 / 32);
    lstm_gemm<<<grid, 256, 0, stream>>>(Xb, Wp, cx, bi, bf, bg, bo, out);
  } else {
    dim3 grid(4096 / 128, 1024 / 32);
    lstm_fused_fb<<<grid, 256, 0, stream>>>(xin, hx, cx, Wi, bi, Wf, bf, Wg, bg, Wo, bo, out);
  }
}

// Round 7
// 219.255 us; speedup vs baseline: 1.0940x; 1.0053x over previous
//
#include <hip/hip_runtime.h>
#include <hip/hip_bf16.h>

// LSTM cell, B=4096, IN=1024, H=1024, K = IN+H = 2048. All I/O float32.
// Pass 1 convert_pack: X=concat(input,hx) -> bf16 Xb; W -> bf16 Wp (rows
//   permuted to (gate,hn)-interleaved tile order).
// Pass 2 lstm_gemm: 128x128 MFMA GEMM, BK=64, single-buffer 2-barrier K-loop,
//   32x32x16 MFMA (16 frag VGPRs vs 64 for 16x16x32) + __launch_bounds__(256,4)
//   => 4 waves/SIMD, grid = one fully-resident round (R6 had 3/SIMD + tail).
//   8-slot XOR swizzle (conflict-free ds_read_b128), fused LSTM epilogue with
//   shfl_xor(16) gate exchange. fp32 accumulate/output.

typedef __attribute__((ext_vector_type(8))) __bf16 bf16x8;
typedef __attribute__((ext_vector_type(16))) float f32x16;

__device__ __forceinline__ unsigned short f2bf(float f) {
  union { float f; unsigned int u; } v; v.f = f;
  unsigned int u = v.u + 0x7FFF + ((v.u >> 16) & 1);  // round-to-nearest-even
  return (unsigned short)(u >> 16);
}
__device__ __forceinline__ unsigned int pack2(float a, float b) {
  return (unsigned int)f2bf(a) | ((unsigned int)f2bf(b) << 16);
}

__device__ __forceinline__ void gld_lds16(const void* g, void* l) {
  __builtin_amdgcn_global_load_lds(
      (const __attribute__((address_space(1))) unsigned int*)g,
      (__attribute__((address_space(3))) unsigned int*)l, 16, 0, 0);
}

__device__ __forceinline__ float sigmoidf_fast(float x) {
  return 1.0f / (1.0f + __expf(-x));
}
__device__ __forceinline__ float tanhf_fast(float x) {
  return 1.0f - 2.0f / (__expf(2.0f * x) + 1.0f);
}

// ---------------- Pass 1: fp32 -> bf16 conversion + W permutation ----------
__global__ __launch_bounds__(256) void convert_pack(
    const float* __restrict__ xin, const float* __restrict__ hx,
    const float* __restrict__ Wi, const float* __restrict__ Wf,
    const float* __restrict__ Wg, const float* __restrict__ Wo,
    unsigned short* __restrict__ Xb, unsigned short* __restrict__ Wp) {
  const int t = blockIdx.x * 256 + threadIdx.x;
  const float* src;
  unsigned short* dst;
  if (t < (1 << 20)) {
    const int e = t * 8;
    const int row = e >> 11, k = e & 2047;
    src = (k < 1024) ? (xin + (size_t)row * 1024 + k)
                     : (hx + (size_t)row * 1024 + (k - 1024));
    dst = Xb + e;
  } else {
    const int e = (t - (1 << 20)) * 8;
    const int g_rb = e >> 11, k = e & 2047;
    const int nb = g_rb >> 7, rb = g_rb & 127;
    const int gate = (rb >> 4) & 3;
    const int hn = (rb >> 6) * 16 + (rb & 15);
    const float* W = gate == 0 ? Wi : (gate == 1 ? Wf : (gate == 2 ? Wg : Wo));
    src = W + (size_t)(nb * 32 + hn) * 2048 + k;
    dst = Wp + e;
  }
  const float4 lo = *(const float4*)src;
  const float4 hi = *(const float4*)(src + 4);
  uint4 p;
  p.x = pack2(lo.x, lo.y);
  p.y = pack2(lo.z, lo.w);
  p.z = pack2(hi.x, hi.y);
  p.w = pack2(hi.z, hi.w);
  *(uint4*)dst = p;
}

// ---------------- Pass 2: MFMA GEMM + fused LSTM gating --------------------
__global__ __launch_bounds__(256, 4) void lstm_gemm(
    const unsigned short* __restrict__ Xb, const unsigned short* __restrict__ Wp,
    const float* __restrict__ cx,
    const float* __restrict__ bi, const float* __restrict__ bfv,
    const float* __restrict__ bg, const float* __restrict__ bo,
    float* __restrict__ out) {
  __shared__ unsigned short As[128 * 64];  // X tile (BK=64), swizzled slots
  __shared__ unsigned short Bs[128 * 64];  // W tile (BK=64), swizzled slots

  const int tid = threadIdx.x;
  const int lane = tid & 63;
  const int wid = tid >> 6;
  const int wr = wid >> 1, wc = wid & 1;
  const int l31 = lane & 31;
  const int hi = lane >> 5;  // k-half within fragment
  const int l7 = l31 & 7;

  const int mbase = blockIdx.x * 128;  // batch tile
  const int nb = blockIdx.y;           // hidden-col tile (32 cols)
  const int nbase = nb * 32;

  // staging (same as R6): slot s holds chunk (s&7)^((s>>3)&7) of row s>>3;
  // thread owns slots tid + 256*d, d=0..3 -> affine sources.
  const int r_base = tid >> 3;
  const int j_sw = (tid & 7) ^ (r_base & 7);
  const unsigned short* asrc = Xb + (size_t)(mbase + r_base) * 2048 + j_sw * 8;
  const unsigned short* bsrc = Wp + (size_t)(nb * 128 + r_base) * 2048 + j_sw * 8;
  unsigned short* lA = As + tid * 8;
  unsigned short* lB = Bs + tid * 8;

  f32x16 acc[2][2] = {};  // [ti][tj], 64 AGPRs total

  // fragment row bases: A row = wr*64 + ti*32 + l31; B row = wc*64 + tj*32 + l31
  const int aro = (wr * 64 + l31) * 64;
  const int bro = (wc * 64 + l31) * 64;

  for (int kt = 0; kt < 32; ++kt) {
    const int kc = kt * 64;
#pragma unroll
    for (int d = 0; d < 4; ++d) {
      gld_lds16(asrc + (size_t)d * (32 * 2048) + kc, lA + d * 2048);
      gld_lds16(bsrc + (size_t)d * (32 * 2048) + kc, lB + d * 2048);
    }
    __syncthreads();  // DMA landed + all waves staged

#pragma unroll
    for (int s = 0; s < 4; ++s) {  // 4 k16-steps per BK=64 tile
      // logical chunk = s*2 + hi; swizzled by row&7 (== l7)
      const int cs = ((s * 2 + hi) ^ l7) * 8;
      bf16x8 a0 = *reinterpret_cast<const bf16x8*>(&As[aro + cs]);
      bf16x8 a1 = *reinterpret_cast<const bf16x8*>(&As[aro + 32 * 64 + cs]);
      bf16x8 b0 = *reinterpret_cast<const bf16x8*>(&Bs[bro + cs]);
      bf16x8 b1 = *reinterpret_cast<const bf16x8*>(&Bs[bro + 32 * 64 + cs]);
      acc[0][0] = __builtin_amdgcn_mfma_f32_32x32x16_bf16(a0, b0, acc[0][0], 0, 0, 0);
      acc[0][1] = __builtin_amdgcn_mfma_f32_32x32x16_bf16(a0, b1, acc[0][1], 0, 0, 0);
      acc[1][0] = __builtin_amdgcn_mfma_f32_32x32x16_bf16(a1, b0, acc[1][0], 0, 0, 0);
      acc[1][1] = __builtin_amdgcn_mfma_f32_32x32x16_bf16(a1, b1, acc[1][1], 0, 0, 0);
    }
    __syncthreads();  // reads done before next iter's DMA overwrites
  }

  // ---- fused LSTM epilogue ----
  // C layout (32x32): col = tj*32 + (lane&31), row = ti*32 + (r&3) + 8*(r>>2)
  //   + 4*(lane>>5). Gate = ((col_local)>>4)&3: lane bit4 (p) selects gate
  //   parity; tj selects {i,f} vs {g,o}. Partner lanes L and L+16 hold the
  //   same (row, hidden-col) for complementary gates -> shfl_xor(16).
  const int p = (l31 >> 4) & 1;  // 0: this lane holds (i,g); 1: (f,o)
  const int n = nbase + wc * 16 + (l31 & 15);
  const float bias0 = p ? bfv[n] : bi[n];
  const float bias1 = p ? bo[n] : bg[n];

  float* outh = out;
  float* outc = out + (size_t)4096 * 1024;

#pragma unroll
  for (int ti = 0; ti < 2; ++ti) {
#pragma unroll
    for (int r = 0; r < 16; ++r) {
      const int row = mbase + wr * 64 + ti * 32 + (r & 3) + 8 * (r >> 2) + 4 * hi;
      const size_t idx = (size_t)row * 1024 + n;
      const float own0 = acc[ti][0][r] + bias0;
      const float own1 = acc[ti][1][r] + bias1;
      const float rcv0 = __shfl_xor(own0, 16);
      const float rcv1 = __shfl_xor(own1, 16);
      const float zi = p ? rcv0 : own0;
      const float zf = p ? own0 : rcv0;
      const float zg = p ? rcv1 : own1;
      const float zo = p ? own1 : rcv1;
      const float it = sigmoidf_fast(zi);
      const float ft = sigmoidf_fast(zf);
      const float gt = tanhf_fast(zg);
      const float ot = sigmoidf_fast(zo);
      const float cv = ft * cx[idx] + it * gt;
      const float hv = ot * tanhf_fast(cv);
      float* dst = p ? (outc + idx) : (outh + idx);
      *dst = p ? cv : hv;
    }
  }
}

// ---------------- Fallback (R2): single fused kernel, no workspace ----------
__global__ __launch_bounds__(256) void lstm_fused_fb(
    const float* __restrict__ xin, const float* __restrict__ hx,
    const float* __restrict__ cx,
    const float* __restrict__ Wi, const float* __restrict__ bi,
    const float* __restrict__ Wf, const float* __restrict__ bfv,
    const float* __restrict__ Wg, const float* __restrict__ bg,
    const float* __restrict__ Wo, const float* __restrict__ bo,
    float* __restrict__ out) {
  typedef __attribute__((ext_vector_type(4))) float f32x4;
  __shared__ unsigned short As[128 * 32];
  __shared__ unsigned short Bs[128 * 32];

  const int tid = threadIdx.x;
  const int lane = tid & 63;
  const int wid = tid >> 6;
  const int wr = wid >> 1, wc = wid & 1;
  const int lane15 = lane & 15, quad = lane >> 4;
  const int mbase = blockIdx.x * 128;
  const int nbase = blockIdx.y * 32;

  const int kofs = (tid & 3) * 8;
  const size_t a_off0 = (size_t)(mbase + (tid >> 2)) * 1024 + kofs;
  const size_t a_off1 = a_off0 + (size_t)64 * 1024;

  auto wsel = [&](int g) { return g == 0 ? Wi : (g == 1 ? Wf : (g == 2 ? Wg : Wo)); };
  const int rb0 = tid >> 2;
  const int rb1 = rb0 + 64;
  const float* bsrc0 =
      wsel((rb0 >> 4) & 3) + (size_t)(nbase + (rb0 >> 6) * 16 + (rb0 & 15)) * 2048 + kofs;
  const float* bsrc1 =
      wsel((rb1 >> 4) & 3) + (size_t)(nbase + (rb1 >> 6) * 16 + (rb1 & 15)) * 2048 + kofs;

  uint4* lA0 = (uint4*)(As + (size_t)tid * 8);
  uint4* lA1 = (uint4*)(As + (size_t)(tid + 256) * 8);
  uint4* lB0 = (uint4*)(Bs + (size_t)tid * 8);
  uint4* lB1 = (uint4*)(Bs + (size_t)(tid + 256) * 8);

  f32x4 acc[4][4] = {};

  for (int kt = 0; kt < 64; ++kt) {
    const int kc = kt * 32;
    const float* abase = (kc < 1024 ? xin : hx) + (kc & 1023);
    const float4 a0lo = *(const float4*)(abase + a_off0);
    const float4 a0hi = *(const float4*)(abase + a_off0 + 4);
    const float4 a1lo = *(const float4*)(abase + a_off1);
    const float4 a1hi = *(const float4*)(abase + a_off1 + 4);
    const float4 b0lo = *(const float4*)(bsrc0 + kc);
    const float4 b0hi = *(const float4*)(bsrc0 + kc + 4);
    const float4 b1lo = *(const float4*)(bsrc1 + kc);
    const float4 b1hi = *(const float4*)(bsrc1 + kc + 4);

    uint4 pa0, pa1, pb0, pb1;
    pa0.x = pack2(a0lo.x, a0lo.y); pa0.y = pack2(a0lo.z, a0lo.w);
    pa0.z = pack2(a0hi.x, a0hi.y); pa0.w = pack2(a0hi.z, a0hi.w);
    pa1.x = pack2(a1lo.x, a1lo.y); pa1.y = pack2(a1lo.z, a1lo.w);
    pa1.z = pack2(a1hi.x, a1hi.y); pa1.w = pack2(a1hi.z, a1hi.w);
    pb0.x = pack2(b0lo.x, b0lo.y); pb0.y = pack2(b0lo.z, b0lo.w);
    pb0.z = pack2(b0hi.x, b0hi.y); pb0.w = pack2(b0hi.z, b0hi.w);
    pb1.x = pack2(b1lo.x, b1lo.y); pb1.y = pack2(b1lo.z, b1lo.w);
    pb1.z = pack2(b1hi.x, b1hi.y); pb1.w = pack2(b1hi.z, b1hi.w);

    __syncthreads();
    *lA0 = pa0; *lA1 = pa1; *lB0 = pb0; *lB1 = pb1;
    __syncthreads();

    bf16x8 a[4], b[4];
#pragma unroll
    for (int i = 0; i < 4; ++i)
      a[i] = *reinterpret_cast<const bf16x8*>(&As[(wr * 64 + i * 16 + lane15) * 32 + quad * 8]);
#pragma unroll
    for (int j = 0; j < 4; ++j)
      b[j] = *reinterpret_cast<const bf16x8*>(&Bs[(wc * 64 + j * 16 + lane15) * 32 + quad * 8]);
#pragma unroll
    for (int i = 0; i < 4; ++i)
#pragma unroll
      for (int j = 0; j < 4; ++j)
        acc[i][j] = __builtin_amdgcn_mfma_f32_16x16x32_bf16(a[i], b[j], acc[i][j], 0, 0, 0);
  }

  const int n = nbase + wc * 16 + lane15;
  const float bias_i = bi[n];
  const float bias_f = bfv[n];
  const float bias_g = bg[n];
  const float bias_o = bo[n];
  float* outh = out;
  float* outc = out + (size_t)4096 * 1024;

#pragma unroll
  for (int i = 0; i < 4; ++i) {
#pragma unroll
    for (int r = 0; r < 4; ++r) {
      const int mb = mbase + wr * 64 + i * 16 + quad * 4 + r;
      const size_t idx = (size_t)mb * 1024 + n;
      const float it = sigmoidf_fast(acc[i][0][r] + bias_i);
      const float ft = sigmoidf_fast(acc[i][1][r] + bias_f);
      const float gt = tanhf_fast(acc[i][2][r] + bias_g);
      const float ot = sigmoidf_fast(acc[i][3][r] + bias_o);
      const float cv = ft * cx[idx] + it * gt;
      const float hv = ot * tanhf_fast(cv);
      outh[idx] = hv;
      outc[idx] = cv;
    }
  }
}

extern "C" void kernel_launch(void* const* d_in, const int* in_sizes, int n_in,
                              void* d_out, int out_size, void* d_ws, size_t ws_size,
                              hipStream_t stream) {
  const float* xin = (const float*)d_in[0];
  const float* hx  = (const float*)d_in[1];
  const float* cx  = (const float*)d_in[2];
  const float* Wi  = (const float*)d_in[3];
  const float* bi  = (const float*)d_in[4];
  const float* Wf  = (const float*)d_in[5];
  const float* bf  = (const float*)d_in[6];
  const float* Wg  = (const float*)d_in[7];
  const float* bg  = (const float*)d_in[8];
  const float* Wo  = (const float*)d_in[9];
  const float* bo  = (const float*)d_in[10];
  float* out = (float*)d_out;

  const size_t need = (size_t)2 * 4096 * 2048 * sizeof(unsigned short);  // 32 MB
  if (ws_size >= need) {
    unsigned short* Xb = (unsigned short*)d_ws;
    unsigned short* Wp = Xb + (size_t)4096 * 2048;
    convert_pack<<<8192, 256, 0, stream>>>(xin, hx, Wi, Wf, Wg, Wo, Xb, Wp);
    dim3 grid(4096 / 128, 1024 / 32);
    lstm_gemm<<<grid, 256, 0, stream>>>(Xb, Wp, cx, bi, bf, bg, bo, out);
  } else {
    dim3 grid(4096 / 128, 1024 / 32);
    lstm_fused_fb<<<grid, 256, 0, stream>>>(xin, hx, cx, Wi, bi, Wf, bf, Wg, bg, Wo, bo, out);
  }
}